// Round 1
// baseline (1238.159 us; speedup 1.0000x reference)
//
#include <hip/hip_runtime.h>

typedef unsigned short u16;
typedef unsigned int u32;
typedef short s16x8 __attribute__((ext_vector_type(8)));
typedef float f32x4 __attribute__((ext_vector_type(4)));

#define T_SEQ 40
#define EMB 300
#define KPAD 320
#define NCOL 3072  // 3H * 2 dirs
#define NTOK 20480 // B*T

__device__ __forceinline__ u16 f2bf(float x) {
  u32 u = __builtin_bit_cast(u32, x);
  u32 r = (u + 0x7fffu + ((u >> 16) & 1u)) >> 16;  // RNE
  return (u16)r;
}
__device__ __forceinline__ float bf2f(u16 h) {
  return __builtin_bit_cast(float, ((u32)h) << 16);
}
__device__ __forceinline__ float sigm(float x) {
  return 1.0f / (1.0f + __expf(-x));
}

// ---- init: d_out = -FLT_MAX (masked-max identity, matches finfo.min), h(parity0) = 0
__global__ void k_init(float* __restrict__ y, u16* __restrict__ h_hi, u16* __restrict__ h_lo) {
  int i = blockIdx.x * 256 + threadIdx.x;
  if (i < 524288) {
    y[i] = -3.402823466e38f;
    h_hi[i] = 0;  // parity-0 region of h_hi/h_lo is exactly 2*512*512 = 524288 elems
    h_lo[i] = 0;
  }
}

// ---- pack w_ih (both dirs) to bf16, K padded 300 -> 320 with zeros
__global__ void k_prep_wih(const float* __restrict__ wf, const float* __restrict__ wb,
                           u16* __restrict__ wih) {
  int n = blockIdx.x, e = threadIdx.x;       // n in [0,3072), e in [0,320)
  int dir = (n >= 1536);
  int g = n - dir * 1536;
  const float* src = dir ? wb : wf;
  float v = (e < EMB) ? src[(size_t)g * EMB + e] : 0.0f;
  wih[(size_t)n * KPAD + e] = f2bf(v);
}

// ---- split w_hh (both dirs) into bf16 hi/lo
__global__ void k_prep_whh(const float* __restrict__ wf, const float* __restrict__ wb,
                           u16* __restrict__ hi, u16* __restrict__ lo) {
  int n = blockIdx.x, k = threadIdx.x;       // n in [0,3072), k in [0,512)
  int dir = (n >= 1536);
  int g = n - dir * 1536;
  float v = (dir ? wb : wf)[(size_t)g * 512 + k];
  u16 h = f2bf(v);
  hi[(size_t)n * 512 + k] = h;
  lo[(size_t)n * 512 + k] = f2bf(v - bf2f(h));
}

__global__ void k_prep_bias(const float* __restrict__ bihf, const float* __restrict__ bihb,
                            const float* __restrict__ bhhf, const float* __restrict__ bhhb,
                            float* __restrict__ bias_ih, float* __restrict__ bias_hh) {
  int i = blockIdx.x * 1024 + threadIdx.x;
  if (i >= 3072) return;
  int dir = (i >= 1536);
  int g = i - dir * 1536;
  bias_ih[i] = dir ? bihb[g] : bihf[g];
  bias_hh[i] = dir ? bhhb[g] : bhhf[g];
}

// ---- phase A: gi[tok][n] = sum_e emb[idx[tok]][e] * wih[n][e] + b_ih[n]
// M=20480, N=3072, K=320. 128x128 block tile, 4 waves (2x2 of 64x64), 16x16x32 MFMA.
__global__ __launch_bounds__(256) void k_gi_gemm(
    const int* __restrict__ idxs, const float* __restrict__ emb,
    const u16* __restrict__ wih, const float* __restrict__ bias_ih,
    void* __restrict__ gi, int gi_f32) {
  __shared__ u16 As[128][40];  // +8 pad: 2-way max bank aliasing (free)
  __shared__ u16 Bs[128][40];
  const int m0 = blockIdx.x * 128;
  const int n0 = blockIdx.y * 128;
  const int t = threadIdx.x;
  const int w = t >> 6, l = t & 63;
  const int wm = (w >> 1) * 64, wn = (w & 1) * 64;
  const int lr = l & 15, lg = l >> 4;

  f32x4 acc[4][4];
#pragma unroll
  for (int i = 0; i < 4; ++i)
#pragma unroll
    for (int j = 0; j < 4; ++j) acc[i][j] = (f32x4)0.0f;

  const int arow = t >> 1, aseg = t & 1;  // A/B stage: row t/2, 16-elem seg t&1
  const int tok = idxs[m0 + arow];
  const float* aerow = emb + (size_t)tok * EMB;
  const u16* brow_p = wih + (size_t)(n0 + arow) * KPAD;

  for (int kc = 0; kc < 10; ++kc) {
    const int k0 = kc * 32;
    {  // stage A: gather emb row, f32 -> bf16
      int cb = k0 + aseg * 16;
      u16* d = &As[arow][aseg * 16];
      if (cb + 15 < EMB) {
        const float4* s = (const float4*)(aerow + cb);
        float4 v0 = s[0], v1 = s[1], v2 = s[2], v3 = s[3];
        uint4 w0, w1;
        w0.x = (u32)f2bf(v0.x) | ((u32)f2bf(v0.y) << 16);
        w0.y = (u32)f2bf(v0.z) | ((u32)f2bf(v0.w) << 16);
        w0.z = (u32)f2bf(v1.x) | ((u32)f2bf(v1.y) << 16);
        w0.w = (u32)f2bf(v1.z) | ((u32)f2bf(v1.w) << 16);
        w1.x = (u32)f2bf(v2.x) | ((u32)f2bf(v2.y) << 16);
        w1.y = (u32)f2bf(v2.z) | ((u32)f2bf(v2.w) << 16);
        w1.z = (u32)f2bf(v3.x) | ((u32)f2bf(v3.y) << 16);
        w1.w = (u32)f2bf(v3.z) | ((u32)f2bf(v3.w) << 16);
        *(uint4*)d = w0;
        *(uint4*)(d + 8) = w1;
      } else {
#pragma unroll
        for (int e = 0; e < 16; ++e) {
          int c = cb + e;
          d[e] = (c < EMB) ? f2bf(aerow[c]) : (u16)0;
        }
      }
    }
    {  // stage B (already bf16)
      const u16* s = brow_p + k0 + aseg * 16;
      u16* d = &Bs[arow][aseg * 16];
      *(uint4*)d = *(const uint4*)s;
      *(uint4*)(d + 8) = *(const uint4*)(s + 8);
    }
    __syncthreads();
    s16x8 av[4], bv[4];
#pragma unroll
    for (int i = 0; i < 4; ++i) av[i] = *(const s16x8*)&As[wm + i * 16 + lr][lg * 8];
#pragma unroll
    for (int j = 0; j < 4; ++j) bv[j] = *(const s16x8*)&Bs[wn + j * 16 + lr][lg * 8];
#pragma unroll
    for (int i = 0; i < 4; ++i)
#pragma unroll
      for (int j = 0; j < 4; ++j)
        acc[i][j] = __builtin_amdgcn_mfma_f32_16x16x32_bf16(av[i], bv[j], acc[i][j], 0, 0, 0);
    __syncthreads();
  }
#pragma unroll
  for (int i = 0; i < 4; ++i) {
#pragma unroll
    for (int j = 0; j < 4; ++j) {
      int n = n0 + wn + j * 16 + lr;
      float b = bias_ih[n];
#pragma unroll
      for (int r = 0; r < 4; ++r) {
        int m = m0 + wm + i * 16 + lg * 4 + r;  // C/D: row=(l>>4)*4+reg, col=l&15 (m89)
        float v = acc[i][j][r] + b;
        if (gi_f32) ((float*)gi)[(size_t)m * NCOL + n] = v;
        else ((u16*)gi)[(size_t)m * NCOL + n] = f2bf(v);
      }
    }
  }
}

// ---- phase B: one GRU step, both dirs. gh = h @ w_hh^T (bf16x3 split), fused gates,
// h double-buffered (parity), running masked max into d_out.
// Block: 64(batch) x 32(hidden j) x 3 gates for one dir; grid 8x16x2 = 256 blocks.
__global__ __launch_bounds__(256) void k_gru_step(
    const u16* __restrict__ whh_hi, const u16* __restrict__ whh_lo,
    const float* __restrict__ bias_hh,
    const void* __restrict__ gi, int gi_f32,
    const int* __restrict__ idxs,
    u16* __restrict__ h_hi, u16* __restrict__ h_lo,
    float* __restrict__ ymax, int s) {
  __shared__ u16 Ah[64][40], Al[64][40];
  __shared__ u16 Bh[96][40], Bl[96][40];
  const int dir = blockIdx.z;
  const int m0 = blockIdx.x * 64;
  const int j0 = blockIdx.y * 32;
  const int t = threadIdx.x, w = t >> 6, l = t & 63;
  const int lr = l & 15, lg = l >> 4;
  const int p = s & 1;
  const size_t HS = 262144;  // 512*512
  const u16* hs_hi = h_hi + (size_t)(p * 2 + dir) * HS;
  const u16* hs_lo = h_lo + (size_t)(p * 2 + dir) * HS;
  u16* hd_hi = h_hi + (size_t)((p ^ 1) * 2 + dir) * HS;
  u16* hd_lo = h_lo + (size_t)((p ^ 1) * 2 + dir) * HS;
  const int wbase = dir * 1536;

  f32x4 acc[3][2];
#pragma unroll
  for (int g = 0; g < 3; ++g)
#pragma unroll
    for (int jt = 0; jt < 2; ++jt) acc[g][jt] = (f32x4)0.0f;

  const int arow = t >> 2, aseg = t & 3;  // A stage: 64 rows x 4 segs of 8
  const size_t abase = (size_t)(m0 + arow) * 512;

  for (int kc = 0; kc < 16; ++kc) {
    const int k0 = kc * 32;
    *(uint4*)&Ah[arow][aseg * 8] = *(const uint4*)(hs_hi + abase + k0 + aseg * 8);
    *(uint4*)&Al[arow][aseg * 8] = *(const uint4*)(hs_lo + abase + k0 + aseg * 8);
    for (int c = t; c < 384; c += 256) {  // B stage: 96 rows (3 gates x 32 j) x 4 segs
      int rr = c >> 2, seg = c & 3;
      int g = rr >> 5, jj = rr & 31;
      size_t off = (size_t)(wbase + g * 512 + j0 + jj) * 512 + k0 + seg * 8;
      *(uint4*)&Bh[rr][seg * 8] = *(const uint4*)(whh_hi + off);
      *(uint4*)&Bl[rr][seg * 8] = *(const uint4*)(whh_lo + off);
    }
    __syncthreads();
    s16x8 ah = *(const s16x8*)&Ah[w * 16 + lr][lg * 8];
    s16x8 al = *(const s16x8*)&Al[w * 16 + lr][lg * 8];
#pragma unroll
    for (int g = 0; g < 3; ++g)
#pragma unroll
      for (int jt = 0; jt < 2; ++jt) {
        s16x8 bh = *(const s16x8*)&Bh[g * 32 + jt * 16 + lr][lg * 8];
        s16x8 bl = *(const s16x8*)&Bl[g * 32 + jt * 16 + lr][lg * 8];
        // f32-equivalent: w_hi*h_hi + w_hi*h_lo + w_lo*h_hi (drop lo*lo ~2^-16)
        acc[g][jt] = __builtin_amdgcn_mfma_f32_16x16x32_bf16(ah, bh, acc[g][jt], 0, 0, 0);
        acc[g][jt] = __builtin_amdgcn_mfma_f32_16x16x32_bf16(al, bh, acc[g][jt], 0, 0, 0);
        acc[g][jt] = __builtin_amdgcn_mfma_f32_16x16x32_bf16(ah, bl, acc[g][jt], 0, 0, 0);
      }
    __syncthreads();
  }

  const int tok = dir ? (T_SEQ - 1 - s) : s;  // backward dir consumes reversed sequence
#pragma unroll
  for (int jt = 0; jt < 2; ++jt) {
    const int j = j0 + jt * 16 + lr;
    const float bR = bias_hh[wbase + j];
    const float bZ = bias_hh[wbase + 512 + j];
    const float bN = bias_hh[wbase + 1024 + j];
#pragma unroll
    for (int r = 0; r < 4; ++r) {
      const int m = m0 + w * 16 + lg * 4 + r;
      const size_t gbase = (size_t)(m * T_SEQ + tok) * NCOL + wbase;
      float ir, iz, inn;
      if (gi_f32) {
        const float* gp = (const float*)gi + gbase;
        ir = gp[j]; iz = gp[512 + j]; inn = gp[1024 + j];
      } else {
        const u16* gp = (const u16*)gi + gbase;
        ir = bf2f(gp[j]); iz = bf2f(gp[512 + j]); inn = bf2f(gp[1024 + j]);
      }
      const size_t hidx = (size_t)m * 512 + j;
      const float hp = bf2f(hs_hi[hidx]) + bf2f(hs_lo[hidx]);
      const float rg = sigm(ir + acc[0][jt][r] + bR);
      const float zg = sigm(iz + acc[1][jt][r] + bZ);
      const float ng = tanhf(inn + rg * (acc[2][jt][r] + bN));
      const float hn = (1.0f - zg) * ng + zg * hp;
      const u16 hhi = f2bf(hn);
      hd_hi[hidx] = hhi;
      hd_lo[hidx] = f2bf(hn - bf2f(hhi));
      if (idxs[m * T_SEQ + tok] != 0) {  // masked running max-pool
        float* yp = ymax + (size_t)m * 1024 + dir * 512 + j;
        *yp = fmaxf(*yp, hn);
      }
    }
  }
}

extern "C" void kernel_launch(void* const* d_in, const int* in_sizes, int n_in,
                              void* d_out, int out_size, void* d_ws, size_t ws_size,
                              hipStream_t stream) {
  const int* idxs = (const int*)d_in[0];
  const float* emb = (const float*)d_in[1];
  const float* wihf = (const float*)d_in[2];
  const float* whhf = (const float*)d_in[3];
  const float* bihf = (const float*)d_in[4];
  const float* bhhf = (const float*)d_in[5];
  const float* wihb = (const float*)d_in[6];
  const float* whhb = (const float*)d_in[7];
  const float* bihb = (const float*)d_in[8];
  const float* bhhb = (const float*)d_in[9];
  float* ymax = (float*)d_out;  // [512][1024] f32, also the running-max accumulator

  char* ws = (char*)d_ws;
  u16* whh_hi = (u16*)(ws + 0);              // 3,145,728 B
  u16* whh_lo = (u16*)(ws + 3145728);        // 3,145,728 B
  u16* wih = (u16*)(ws + 6291456);           // 1,966,080 B
  float* bias_ih = (float*)(ws + 8257536);   // 12,288 B
  float* bias_hh = (float*)(ws + 8269824);   // 12,288 B
  u16* h_hi = (u16*)(ws + 8282112);          // 2,097,152 B  [parity][dir][512][512]
  u16* h_lo = (u16*)(ws + 10379264);         // 2,097,152 B
  void* gi = (void*)(ws + 12476416);         // f32: 251.7 MB, bf16: 125.8 MB
  const int gi_f32 = (ws_size >= 12476416ull + 251658240ull) ? 1 : 0;

  k_init<<<2048, 256, 0, stream>>>(ymax, h_hi, h_lo);
  k_prep_wih<<<3072, 320, 0, stream>>>(wihf, wihb, wih);
  k_prep_whh<<<3072, 512, 0, stream>>>(whhf, whhb, whh_hi, whh_lo);
  k_prep_bias<<<3, 1024, 0, stream>>>(bihf, bihb, bhhf, bhhb, bias_ih, bias_hh);
  k_gi_gemm<<<dim3(160, 24), 256, 0, stream>>>(idxs, emb, wih, bias_ih, gi, gi_f32);
  for (int s = 0; s < T_SEQ; ++s)
    k_gru_step<<<dim3(8, 16, 2), 256, 0, stream>>>(whh_hi, whh_lo, bias_hh, gi, gi_f32,
                                                   idxs, h_hi, h_lo, ymax, s);
}

// Round 2
// 1063.696 us; speedup vs baseline: 1.1640x; 1.1640x over previous
//
#include <hip/hip_runtime.h>

typedef unsigned short u16;
typedef unsigned int u32;
typedef unsigned long long u64;
typedef short s16x8 __attribute__((ext_vector_type(8)));
typedef float f32x4 __attribute__((ext_vector_type(4)));

#define T_SEQ 40
#define EMB 300
#define KPAD 320
#define NCOL 3072   // 3H * 2 dirs
#define NTOK 20480  // B*T
#define HS 262144   // 512*512 (one dir, one parity)

__device__ __forceinline__ u16 f2bf(float x) {
  u32 u = __builtin_bit_cast(u32, x);
  u32 r = (u + 0x7fffu + ((u >> 16) & 1u)) >> 16;  // RNE
  return (u16)r;
}
__device__ __forceinline__ float bf2f(u16 h) {
  return __builtin_bit_cast(float, ((u32)h) << 16);
}
__device__ __forceinline__ float sigm(float x) {
  return 1.0f / (1.0f + __expf(-x));
}

// ---- init: zero h parity-0 (both dirs, hi+lo), barrier counters, build per-row mask bitmaps
__global__ void k_init(const int* __restrict__ idxs, u16* __restrict__ h_hi,
                       u16* __restrict__ h_lo, u64* __restrict__ mask, int* __restrict__ bar) {
  int i = blockIdx.x * 256 + threadIdx.x;
  if (i < 2 * HS) { h_hi[i] = 0; h_lo[i] = 0; }
  if (i < 256) bar[i] = 0;
  if (i < 512) {
    u64 b = 0;
    for (int t = 0; t < T_SEQ; ++t)
      if (idxs[i * T_SEQ + t] != 0) b |= (1ull << t);
    mask[i] = b;
  }
}

// ---- emb f32 [V][300] -> bf16 [V][320] (zero-padded), done once
__global__ void k_prep_emb(const float* __restrict__ emb, u16* __restrict__ emb16) {
  for (int idx = blockIdx.x * 256 + threadIdx.x; idx < 50000 * 160; idx += 4096 * 256) {
    int row = idx / 160, c2 = idx - row * 160;
    int c0 = 2 * c2;
    float v0 = (c0 < EMB) ? emb[(size_t)row * EMB + c0] : 0.0f;
    float v1 = (c0 + 1 < EMB) ? emb[(size_t)row * EMB + c0 + 1] : 0.0f;
    ((u32*)emb16)[(size_t)row * 160 + c2] = (u32)f2bf(v0) | ((u32)f2bf(v1) << 16);
  }
}

// ---- pack w_ih (both dirs) to bf16, K padded 300 -> 320
__global__ void k_prep_wih(const float* __restrict__ wf, const float* __restrict__ wb,
                           u16* __restrict__ wih) {
  int n = blockIdx.x, e = threadIdx.x;
  int dir = (n >= 1536);
  int g = n - dir * 1536;
  const float* src = dir ? wb : wf;
  float v = (e < EMB) ? src[(size_t)g * EMB + e] : 0.0f;
  wih[(size_t)n * KPAD + e] = f2bf(v);
}

// ---- split w_hh (both dirs) into bf16 hi/lo
__global__ void k_prep_whh(const float* __restrict__ wf, const float* __restrict__ wb,
                           u16* __restrict__ hi, u16* __restrict__ lo) {
  int n = blockIdx.x, k = threadIdx.x;
  int dir = (n >= 1536);
  int g = n - dir * 1536;
  float v = (dir ? wb : wf)[(size_t)g * 512 + k];
  u16 h = f2bf(v);
  hi[(size_t)n * 512 + k] = h;
  lo[(size_t)n * 512 + k] = f2bf(v - bf2f(h));
}

__global__ void k_prep_bias(const float* __restrict__ bihf, const float* __restrict__ bihb,
                            const float* __restrict__ bhhf, const float* __restrict__ bhhb,
                            float* __restrict__ bias_ih, float* __restrict__ bias_hh) {
  int i = blockIdx.x * 1024 + threadIdx.x;
  if (i >= 3072) return;
  int dir = (i >= 1536);
  int g = i - dir * 1536;
  bias_ih[i] = dir ? bihb[g] : bihf[g];
  bias_hh[i] = dir ? bhhb[g] : bhhf[g];
}

// ---- phase A: gi[tok][n] = emb16[idx[tok]] . wih[n] + b_ih[n], output bf16.
// M=20480, N=3072, K=320; 128x128 tile, 4 waves, 16x16x32 MFMA; C staged via LDS.
__global__ __launch_bounds__(256) void k_gi_gemm(
    const int* __restrict__ idxs, const float* __restrict__ emb,
    const u16* __restrict__ emb16, int use_emb16,
    const u16* __restrict__ wih, const float* __restrict__ bias_ih,
    u16* __restrict__ gi) {
  __shared__ __align__(16) char smem[34816];
  u16(*As)[40] = (u16(*)[40])smem;            // 10240 B
  u16(*Bs)[40] = (u16(*)[40])(smem + 10240);  // 10240 B
  u16(*Cs)[136] = (u16(*)[136])smem;          // 34816 B (reused after K loop)

  const int m0 = blockIdx.x * 128;
  const int n0 = blockIdx.y * 128;
  const int t = threadIdx.x;
  const int w = t >> 6, l = t & 63;
  const int wm = (w >> 1) * 64, wn = (w & 1) * 64;
  const int lr = l & 15, lg = l >> 4;

  f32x4 acc[4][4];
#pragma unroll
  for (int i = 0; i < 4; ++i)
#pragma unroll
    for (int j = 0; j < 4; ++j) acc[i][j] = (f32x4)0.0f;

  const int arow = t >> 1, aseg = t & 1;
  const int tok = idxs[m0 + arow];
  const float* aerow = emb + (size_t)tok * EMB;
  const u16* aerow16 = emb16 + (size_t)tok * KPAD;
  const u16* brow_p = wih + (size_t)(n0 + arow) * KPAD;

  for (int kc = 0; kc < 10; ++kc) {
    const int k0 = kc * 32;
    if (use_emb16) {
      *(uint4*)&As[arow][aseg * 16] = *(const uint4*)(aerow16 + k0 + aseg * 16);
      *(uint4*)(&As[arow][aseg * 16] + 8) = *(const uint4*)(aerow16 + k0 + aseg * 16 + 8);
    } else {
      int cb = k0 + aseg * 16;
      u16* d = &As[arow][aseg * 16];
      if (cb + 15 < EMB) {
        const float4* s = (const float4*)(aerow + cb);
        float4 v0 = s[0], v1 = s[1], v2 = s[2], v3 = s[3];
        uint4 w0, w1;
        w0.x = (u32)f2bf(v0.x) | ((u32)f2bf(v0.y) << 16);
        w0.y = (u32)f2bf(v0.z) | ((u32)f2bf(v0.w) << 16);
        w0.z = (u32)f2bf(v1.x) | ((u32)f2bf(v1.y) << 16);
        w0.w = (u32)f2bf(v1.z) | ((u32)f2bf(v1.w) << 16);
        w1.x = (u32)f2bf(v2.x) | ((u32)f2bf(v2.y) << 16);
        w1.y = (u32)f2bf(v2.z) | ((u32)f2bf(v2.w) << 16);
        w1.z = (u32)f2bf(v3.x) | ((u32)f2bf(v3.y) << 16);
        w1.w = (u32)f2bf(v3.z) | ((u32)f2bf(v3.w) << 16);
        *(uint4*)d = w0;
        *(uint4*)(d + 8) = w1;
      } else {
#pragma unroll
        for (int e = 0; e < 16; ++e) {
          int c = cb + e;
          d[e] = (c < EMB) ? f2bf(aerow[c]) : (u16)0;
        }
      }
    }
    {
      const u16* s = brow_p + k0 + aseg * 16;
      u16* d = &Bs[arow][aseg * 16];
      *(uint4*)d = *(const uint4*)s;
      *(uint4*)(d + 8) = *(const uint4*)(s + 8);
    }
    __syncthreads();
    s16x8 av[4], bv[4];
#pragma unroll
    for (int i = 0; i < 4; ++i) av[i] = *(const s16x8*)&As[wm + i * 16 + lr][lg * 8];
#pragma unroll
    for (int j = 0; j < 4; ++j) bv[j] = *(const s16x8*)&Bs[wn + j * 16 + lr][lg * 8];
#pragma unroll
    for (int i = 0; i < 4; ++i)
#pragma unroll
      for (int j = 0; j < 4; ++j)
        acc[i][j] = __builtin_amdgcn_mfma_f32_16x16x32_bf16(av[i], bv[j], acc[i][j], 0, 0, 0);
    __syncthreads();
  }

  float bj[4];
#pragma unroll
  for (int j = 0; j < 4; ++j) bj[j] = bias_ih[n0 + wn + j * 16 + lr];
#pragma unroll
  for (int i = 0; i < 4; ++i)
#pragma unroll
    for (int j = 0; j < 4; ++j)
#pragma unroll
      for (int r = 0; r < 4; ++r)
        Cs[wm + i * 16 + lg * 4 + r][wn + j * 16 + lr] = f2bf(acc[i][j][r] + bj[j]);
  __syncthreads();
#pragma unroll
  for (int rr = t >> 4; rr < 128; rr += 16) {
    const int cseg = (t & 15) * 8;
    *(uint4*)(gi + (size_t)(m0 + rr) * NCOL + n0 + cseg) = *(const uint4*)&Cs[rr][cseg];
  }
}

// ---- phase B: persistent bidirectional GRU. 256 blocks (1/CU, enforced by 96KB LDS),
// 512 threads (8 waves x 16 rows). Block = (m-tile 128, dir, 16 j's); w_hh hi/lo slice
// lives in LDS in fragment order for all 40 steps. Per-(m-tile,dir) group barrier (32
// blocks, mapped to one XCD via bid%8).
__global__ __launch_bounds__(512, 2) void k_gru_persist(
    const u16* __restrict__ whh_hi, const u16* __restrict__ whh_lo,
    const float* __restrict__ bias_hh, const u16* __restrict__ gi,
    const u64* __restrict__ mask,
    u16* __restrict__ h_hi, u16* __restrict__ h_lo,
    float* __restrict__ ymax, int* __restrict__ bar) {
  extern __shared__ u16 wlds[];  // [64 kcg][48 col][8] hi at 0, lo at 24576 (u16 units)
  const int bid = blockIdx.x;
  const int G = bid & 7;        // group id == best-effort XCD id
  const int jt = bid >> 3;      // 0..31
  const int mt = G >> 1, dir = G & 1;
  const int m0 = mt * 128, j0 = jt * 16;
  const int wbase = dir * 1536;
  const int t = threadIdx.x;
  const int w = t >> 6, l = t & 63, lr = l & 15, lg = l >> 4;

  for (int c = t; c < 3072; c += 512) {
    const int col = c % 48, kcg = c / 48;
    const int g = col >> 4, jj = col & 15;
    const int k = (kcg >> 2) * 32 + (kcg & 3) * 8;
    const size_t off = (size_t)(wbase + g * 512 + j0 + jj) * 512 + k;
    *(uint4*)&wlds[c * 8] = *(const uint4*)(whh_hi + off);
    *(uint4*)&wlds[24576 + c * 8] = *(const uint4*)(whh_lo + off);
  }
  const int j = j0 + lr;
  const float bR = bias_hh[wbase + j];
  const float bZ = bias_hh[wbase + 512 + j];
  const float bN = bias_hh[wbase + 1024 + j];
  u64 mk[4];
  float hprev[4], ym[4];
#pragma unroll
  for (int r = 0; r < 4; ++r) {
    mk[r] = mask[m0 + w * 16 + lg * 4 + r];
    hprev[r] = 0.0f;
    ym[r] = -3.402823466e38f;
  }
  __syncthreads();

  const size_t abase = (size_t)(m0 + w * 16 + lr) * 512 + lg * 8;
  for (int s = 0; s < T_SEQ; ++s) {
    const int p = s & 1;
    const u16* hs_hi = h_hi + (size_t)(p * 2 + dir) * HS;
    const u16* hs_lo = h_lo + (size_t)(p * 2 + dir) * HS;
    u16* hd_hi = h_hi + (size_t)((p ^ 1) * 2 + dir) * HS;
    u16* hd_lo = h_lo + (size_t)((p ^ 1) * 2 + dir) * HS;
    const int tok = dir ? (T_SEQ - 1 - s) : s;

    // prefetch gi for this step (independent of h)
    u16 gr[4], gz[4], gn[4];
#pragma unroll
    for (int r = 0; r < 4; ++r) {
      const int m = m0 + w * 16 + lg * 4 + r;
      const size_t gb = ((size_t)m * T_SEQ + tok) * NCOL + wbase + j;
      gr[r] = gi[gb];
      gz[r] = gi[gb + 512];
      gn[r] = gi[gb + 1024];
    }

    f32x4 acc[3];
    acc[0] = acc[1] = acc[2] = (f32x4)0.0f;
#pragma unroll
    for (int kc = 0; kc < 16; ++kc) {
      const s16x8 ah = *(const s16x8*)(hs_hi + abase + kc * 32);
      const s16x8 al = *(const s16x8*)(hs_lo + abase + kc * 32);
      const int bbase = ((kc * 4 + lg) * 48 + lr) * 8;
#pragma unroll
      for (int g = 0; g < 3; ++g) {
        const s16x8 bh = *(const s16x8*)&wlds[bbase + g * 128];
        const s16x8 bl = *(const s16x8*)&wlds[24576 + bbase + g * 128];
        acc[g] = __builtin_amdgcn_mfma_f32_16x16x32_bf16(ah, bh, acc[g], 0, 0, 0);
        acc[g] = __builtin_amdgcn_mfma_f32_16x16x32_bf16(al, bh, acc[g], 0, 0, 0);
        acc[g] = __builtin_amdgcn_mfma_f32_16x16x32_bf16(ah, bl, acc[g], 0, 0, 0);
      }
    }

#pragma unroll
    for (int r = 0; r < 4; ++r) {
      const int m = m0 + w * 16 + lg * 4 + r;
      const float rg = sigm(bf2f(gr[r]) + acc[0][r] + bR);
      const float zg = sigm(bf2f(gz[r]) + acc[1][r] + bZ);
      const float ng = tanhf(bf2f(gn[r]) + rg * (acc[2][r] + bN));
      const float hn = (1.0f - zg) * ng + zg * hprev[r];
      hprev[r] = hn;
      const size_t hidx = (size_t)m * 512 + j;
      const u16 hh = f2bf(hn);
      hd_hi[hidx] = hh;
      hd_lo[hidx] = f2bf(hn - bf2f(hh));
      if ((mk[r] >> tok) & 1ull) ym[r] = fmaxf(ym[r], hn);
    }

    if (s < T_SEQ - 1) {
      __syncthreads();  // all waves' h stores issued
      if (t == 0) {
        __threadfence();  // make group's h writes agent-visible
        __hip_atomic_fetch_add(&bar[G * 32], 1, __ATOMIC_RELEASE, __HIP_MEMORY_SCOPE_AGENT);
        const int target = 32 * (s + 1);
        while (__hip_atomic_load(&bar[G * 32], __ATOMIC_RELAXED, __HIP_MEMORY_SCOPE_AGENT) <
               target)
          __builtin_amdgcn_s_sleep(1);
        __threadfence();  // acquire: invalidate stale cached h
      }
      __syncthreads();
    }
  }

#pragma unroll
  for (int r = 0; r < 4; ++r) {
    const int m = m0 + w * 16 + lg * 4 + r;
    ymax[(size_t)m * 1024 + dir * 512 + j] = ym[r];
  }
}

extern "C" void kernel_launch(void* const* d_in, const int* in_sizes, int n_in,
                              void* d_out, int out_size, void* d_ws, size_t ws_size,
                              hipStream_t stream) {
  const int* idxs = (const int*)d_in[0];
  const float* emb = (const float*)d_in[1];
  const float* wihf = (const float*)d_in[2];
  const float* whhf = (const float*)d_in[3];
  const float* bihf = (const float*)d_in[4];
  const float* bhhf = (const float*)d_in[5];
  const float* wihb = (const float*)d_in[6];
  const float* whhb = (const float*)d_in[7];
  const float* bihb = (const float*)d_in[8];
  const float* bhhb = (const float*)d_in[9];
  float* ymax = (float*)d_out;  // [512][1024] f32

  char* ws = (char*)d_ws;
  u16* whh_hi = (u16*)(ws + 0);              //   3,145,728
  u16* whh_lo = (u16*)(ws + 3145728);        //   3,145,728
  u16* wih = (u16*)(ws + 6291456);           //   1,966,080
  float* bias_ih = (float*)(ws + 8257536);   //      12,288
  float* bias_hh = (float*)(ws + 8269824);   //      12,288
  u16* h_hi = (u16*)(ws + 8282112);          //   2,097,152  [parity][dir][512][512]
  u16* h_lo = (u16*)(ws + 10379264);         //   2,097,152
  u64* mask = (u64*)(ws + 12476416);         //       4,096
  int* bar = (int*)(ws + 12480512);          //       1,024
  u16* gi = (u16*)(ws + 12481536);           // 125,829,120  bf16 [20480][3072]
  u16* emb16 = (u16*)(ws + 138310656);       //  32,000,000  bf16 [50000][320]
  const int use_emb16 = (ws_size >= 170310656ull) ? 1 : 0;

  k_init<<<2048, 256, 0, stream>>>(idxs, h_hi, h_lo, mask, bar);
  if (use_emb16) k_prep_emb<<<4096, 256, 0, stream>>>(emb, emb16);
  k_prep_wih<<<3072, 320, 0, stream>>>(wihf, wihb, wih);
  k_prep_whh<<<3072, 512, 0, stream>>>(whhf, whhb, whh_hi, whh_lo);
  k_prep_bias<<<3, 1024, 0, stream>>>(bihf, bihb, bhhf, bhhb, bias_ih, bias_hh);
  k_gi_gemm<<<dim3(160, 24), 256, 0, stream>>>(idxs, emb, emb16, use_emb16, wih, bias_ih, gi);

  hipFuncSetAttribute((const void*)k_gru_persist,
                      hipFuncAttributeMaxDynamicSharedMemorySize, 98304);
  k_gru_persist<<<dim3(256), dim3(512), 98304, stream>>>(whh_hi, whh_lo, bias_hh, gi, mask,
                                                         h_hi, h_lo, ymax, bar);
}

// Round 3
// 764.972 us; speedup vs baseline: 1.6186x; 1.3905x over previous
//
#include <hip/hip_runtime.h>

typedef unsigned short u16;
typedef unsigned int u32;
typedef unsigned long long u64;
typedef short s16x8 __attribute__((ext_vector_type(8)));
typedef float f32x4 __attribute__((ext_vector_type(4)));

#define T_SEQ 40
#define EMB 300
#define KPAD 320
#define NCOL 3072   // 3H * 2 dirs
#define HS 262144   // 512*512 elems (one dir, one parity)

__device__ __forceinline__ u16 f2bf(float x) {
  u32 u = __builtin_bit_cast(u32, x);
  u32 r = (u + 0x7fffu + ((u >> 16) & 1u)) >> 16;  // RNE
  return (u16)r;
}
__device__ __forceinline__ float bf2f(u16 h) {
  return __builtin_bit_cast(float, ((u32)h) << 16);
}
__device__ __forceinline__ float sigm(float x) {
  return 1.0f / (1.0f + __expf(-x));
}
// ---- L3-coherent (cross-XCD) access: relaxed agent-scope atomics -> sc0 sc1, bypass L1/L2
__device__ __forceinline__ void coh_st32(u32* p, u32 v) {
  __hip_atomic_store(p, v, __ATOMIC_RELAXED, __HIP_MEMORY_SCOPE_AGENT);
}
__device__ __forceinline__ u64 coh_ld64(const u64* p) {
  return __hip_atomic_load((u64*)p, __ATOMIC_RELAXED, __HIP_MEMORY_SCOPE_AGENT);
}

// ---- init: zero packed h parity-0 (both dirs) + barrier counters (coherent), mask bitmaps
__global__ void k_init(const int* __restrict__ idxs, u32* __restrict__ hpk,
                       u64* __restrict__ mask, int* __restrict__ bar) {
  int i = blockIdx.x * 256 + threadIdx.x;
  if (i < 2 * HS) coh_st32(&hpk[i], 0u);  // parity-0 region = first 2*HS u32
  if (i < 256) coh_st32((u32*)&bar[i], 0u);
  if (i < 512) {
    u64 b = 0;
    for (int t = 0; t < T_SEQ; ++t)
      if (idxs[i * T_SEQ + t] != 0) b |= (1ull << t);
    mask[i] = b;
  }
}

// ---- emb f32 [V][300] -> bf16 [V][320] (zero-padded), done once
__global__ void k_prep_emb(const float* __restrict__ emb, u16* __restrict__ emb16) {
  for (int idx = blockIdx.x * 256 + threadIdx.x; idx < 50000 * 160; idx += 4096 * 256) {
    int row = idx / 160, c2 = idx - row * 160;
    int c0 = 2 * c2;
    float v0 = (c0 < EMB) ? emb[(size_t)row * EMB + c0] : 0.0f;
    float v1 = (c0 + 1 < EMB) ? emb[(size_t)row * EMB + c0 + 1] : 0.0f;
    ((u32*)emb16)[(size_t)row * 160 + c2] = (u32)f2bf(v0) | ((u32)f2bf(v1) << 16);
  }
}

// ---- pack w_ih (both dirs) to bf16, K padded 300 -> 320
__global__ void k_prep_wih(const float* __restrict__ wf, const float* __restrict__ wb,
                           u16* __restrict__ wih) {
  int n = blockIdx.x, e = threadIdx.x;
  int dir = (n >= 1536);
  int g = n - dir * 1536;
  const float* src = dir ? wb : wf;
  float v = (e < EMB) ? src[(size_t)g * EMB + e] : 0.0f;
  wih[(size_t)n * KPAD + e] = f2bf(v);
}

// ---- split w_hh (both dirs) into bf16 hi/lo
__global__ void k_prep_whh(const float* __restrict__ wf, const float* __restrict__ wb,
                           u16* __restrict__ hi, u16* __restrict__ lo) {
  int n = blockIdx.x, k = threadIdx.x;
  int dir = (n >= 1536);
  int g = n - dir * 1536;
  float v = (dir ? wb : wf)[(size_t)g * 512 + k];
  u16 h = f2bf(v);
  hi[(size_t)n * 512 + k] = h;
  lo[(size_t)n * 512 + k] = f2bf(v - bf2f(h));
}

__global__ void k_prep_bias(const float* __restrict__ bihf, const float* __restrict__ bihb,
                            const float* __restrict__ bhhf, const float* __restrict__ bhhb,
                            float* __restrict__ bias_ih, float* __restrict__ bias_hh) {
  int i = blockIdx.x * 1024 + threadIdx.x;
  if (i >= 3072) return;
  int dir = (i >= 1536);
  int g = i - dir * 1536;
  bias_ih[i] = dir ? bihb[g] : bihf[g];
  bias_hh[i] = dir ? bhhb[g] : bhhf[g];
}

// ---- phase A: gi[tok][n] = emb16[idx[tok]] . wih[n] + b_ih[n], output bf16.
// M=20480, N=3072, K=320; 128x128 tile, 4 waves, 16x16x32 MFMA; C staged via LDS.
__global__ __launch_bounds__(256) void k_gi_gemm(
    const int* __restrict__ idxs, const float* __restrict__ emb,
    const u16* __restrict__ emb16, int use_emb16,
    const u16* __restrict__ wih, const float* __restrict__ bias_ih,
    u16* __restrict__ gi) {
  __shared__ __align__(16) char smem[34816];
  u16(*As)[40] = (u16(*)[40])smem;            // 10240 B
  u16(*Bs)[40] = (u16(*)[40])(smem + 10240);  // 10240 B
  u16(*Cs)[136] = (u16(*)[136])smem;          // 34816 B (reused after K loop)

  const int m0 = blockIdx.x * 128;
  const int n0 = blockIdx.y * 128;
  const int t = threadIdx.x;
  const int w = t >> 6, l = t & 63;
  const int wm = (w >> 1) * 64, wn = (w & 1) * 64;
  const int lr = l & 15, lg = l >> 4;

  f32x4 acc[4][4];
#pragma unroll
  for (int i = 0; i < 4; ++i)
#pragma unroll
    for (int j = 0; j < 4; ++j) acc[i][j] = (f32x4)0.0f;

  const int arow = t >> 1, aseg = t & 1;
  const int tok = idxs[m0 + arow];
  const float* aerow = emb + (size_t)tok * EMB;
  const u16* aerow16 = emb16 + (size_t)tok * KPAD;
  const u16* brow_p = wih + (size_t)(n0 + arow) * KPAD;

  for (int kc = 0; kc < 10; ++kc) {
    const int k0 = kc * 32;
    if (use_emb16) {
      *(uint4*)&As[arow][aseg * 16] = *(const uint4*)(aerow16 + k0 + aseg * 16);
      *(uint4*)(&As[arow][aseg * 16] + 8) = *(const uint4*)(aerow16 + k0 + aseg * 16 + 8);
    } else {
      int cb = k0 + aseg * 16;
      u16* d = &As[arow][aseg * 16];
      if (cb + 15 < EMB) {
        const float4* s = (const float4*)(aerow + cb);
        float4 v0 = s[0], v1 = s[1], v2 = s[2], v3 = s[3];
        uint4 w0, w1;
        w0.x = (u32)f2bf(v0.x) | ((u32)f2bf(v0.y) << 16);
        w0.y = (u32)f2bf(v0.z) | ((u32)f2bf(v0.w) << 16);
        w0.z = (u32)f2bf(v1.x) | ((u32)f2bf(v1.y) << 16);
        w0.w = (u32)f2bf(v1.z) | ((u32)f2bf(v1.w) << 16);
        w1.x = (u32)f2bf(v2.x) | ((u32)f2bf(v2.y) << 16);
        w1.y = (u32)f2bf(v2.z) | ((u32)f2bf(v2.w) << 16);
        w1.z = (u32)f2bf(v3.x) | ((u32)f2bf(v3.y) << 16);
        w1.w = (u32)f2bf(v3.z) | ((u32)f2bf(v3.w) << 16);
        *(uint4*)d = w0;
        *(uint4*)(d + 8) = w1;
      } else {
#pragma unroll
        for (int e = 0; e < 16; ++e) {
          int c = cb + e;
          d[e] = (c < EMB) ? f2bf(aerow[c]) : (u16)0;
        }
      }
    }
    {
      const u16* s = brow_p + k0 + aseg * 16;
      u16* d = &Bs[arow][aseg * 16];
      *(uint4*)d = *(const uint4*)s;
      *(uint4*)(d + 8) = *(const uint4*)(s + 8);
    }
    __syncthreads();
    s16x8 av[4], bv[4];
#pragma unroll
    for (int i = 0; i < 4; ++i) av[i] = *(const s16x8*)&As[wm + i * 16 + lr][lg * 8];
#pragma unroll
    for (int j = 0; j < 4; ++j) bv[j] = *(const s16x8*)&Bs[wn + j * 16 + lr][lg * 8];
#pragma unroll
    for (int i = 0; i < 4; ++i)
#pragma unroll
      for (int j = 0; j < 4; ++j)
        acc[i][j] = __builtin_amdgcn_mfma_f32_16x16x32_bf16(av[i], bv[j], acc[i][j], 0, 0, 0);
    __syncthreads();
  }

  float bj[4];
#pragma unroll
  for (int j = 0; j < 4; ++j) bj[j] = bias_ih[n0 + wn + j * 16 + lr];
#pragma unroll
  for (int i = 0; i < 4; ++i)
#pragma unroll
    for (int j = 0; j < 4; ++j)
#pragma unroll
      for (int r = 0; r < 4; ++r)
        Cs[wm + i * 16 + lg * 4 + r][wn + j * 16 + lr] = f2bf(acc[i][j][r] + bj[j]);
  __syncthreads();
#pragma unroll
  for (int rr = t >> 4; rr < 128; rr += 16) {
    const int cseg = (t & 15) * 8;
    *(uint4*)(gi + (size_t)(m0 + rr) * NCOL + n0 + cseg) = *(const uint4*)&Cs[rr][cseg];
  }
}

// ---- phase B: persistent bidirectional GRU. 256 blocks (1/CU via 96KB LDS), 512 thr.
// Block = (m-tile 128, dir, 16 j's); w_hh hi/lo slice in LDS for all 40 steps.
// h exchanged fence-free through L3: packed u32 (hi|lo<<16), sc0+sc1 stores/loads
// (relaxed agent atomics). Group barrier = relaxed agent counter, no cache flushes.
__global__ __launch_bounds__(512, 2) void k_gru_persist(
    const u16* __restrict__ whh_hi, const u16* __restrict__ whh_lo,
    const float* __restrict__ bias_hh, const u16* __restrict__ gi,
    const u64* __restrict__ mask, u32* __restrict__ hpk,
    float* __restrict__ ymax, int* __restrict__ bar) {
  extern __shared__ u16 wlds[];  // [64 kcg][48 col][8] hi at 0, lo at 24576 (u16 units)
  const int bid = blockIdx.x;
  const int G = bid & 7;        // group id (best-effort XCD affinity for gi/L2 locality)
  const int jt = bid >> 3;      // 0..31
  const int mt = G >> 1, dir = G & 1;
  const int m0 = mt * 128, j0 = jt * 16;
  const int wbase = dir * 1536;
  const int t = threadIdx.x;
  const int w = t >> 6, l = t & 63, lr = l & 15, lg = l >> 4;

  for (int c = t; c < 3072; c += 512) {
    const int col = c % 48, kcg = c / 48;
    const int g = col >> 4, jj = col & 15;
    const int k = (kcg >> 2) * 32 + (kcg & 3) * 8;
    const size_t off = (size_t)(wbase + g * 512 + j0 + jj) * 512 + k;
    *(uint4*)&wlds[c * 8] = *(const uint4*)(whh_hi + off);
    *(uint4*)&wlds[24576 + c * 8] = *(const uint4*)(whh_lo + off);
  }
  const int j = j0 + lr;
  const float bR = bias_hh[wbase + j];
  const float bZ = bias_hh[wbase + 512 + j];
  const float bN = bias_hh[wbase + 1024 + j];
  u64 mk[4];
  float hprev[4], ym[4];
#pragma unroll
  for (int r = 0; r < 4; ++r) {
    mk[r] = mask[m0 + w * 16 + lg * 4 + r];
    hprev[r] = 0.0f;
    ym[r] = -3.402823466e38f;
  }
  __syncthreads();

  const size_t abase = (size_t)(m0 + w * 16 + lr) * 512 + lg * 8;  // u32 elems
  for (int s = 0; s < T_SEQ; ++s) {
    const int p = s & 1;
    const u32* hs = hpk + (size_t)(p * 2 + dir) * HS;
    u32* hd = hpk + (size_t)((p ^ 1) * 2 + dir) * HS;
    const int tok = dir ? (T_SEQ - 1 - s) : s;

    // prefetch gi for this step (normal cached loads; gi is read-only)
    u16 gr[4], gz[4], gn[4];
#pragma unroll
    for (int r = 0; r < 4; ++r) {
      const int m = m0 + w * 16 + lg * 4 + r;
      const size_t gb = ((size_t)m * T_SEQ + tok) * NCOL + wbase + j;
      gr[r] = gi[gb];
      gz[r] = gi[gb + 512];
      gn[r] = gi[gb + 1024];
    }

    f32x4 acc[3];
    acc[0] = acc[1] = acc[2] = (f32x4)0.0f;
#pragma unroll
    for (int kc = 0; kc < 16; ++kc) {
      // coherent 32B read of packed h (8 k's), then split hi/lo in-register
      const u64* ap = (const u64*)(hs + abase + kc * 32);
      u64 q0 = coh_ld64(ap), q1 = coh_ld64(ap + 1), q2 = coh_ld64(ap + 2), q3 = coh_ld64(ap + 3);
      u32 hw[8];
      *(u64*)&hw[0] = q0; *(u64*)&hw[2] = q1; *(u64*)&hw[4] = q2; *(u64*)&hw[6] = q3;
      u32 ahw[4], alw[4];
#pragma unroll
      for (int i = 0; i < 4; ++i) {
        ahw[i] = (hw[2 * i] & 0xFFFFu) | (hw[2 * i + 1] << 16);
        alw[i] = (hw[2 * i] >> 16) | (hw[2 * i + 1] & 0xFFFF0000u);
      }
      const s16x8 ah = __builtin_bit_cast(s16x8, *(uint4*)ahw);
      const s16x8 al = __builtin_bit_cast(s16x8, *(uint4*)alw);
      const int bbase = ((kc * 4 + lg) * 48 + lr) * 8;
#pragma unroll
      for (int g = 0; g < 3; ++g) {
        const s16x8 bh = *(const s16x8*)&wlds[bbase + g * 128];
        const s16x8 bl = *(const s16x8*)&wlds[24576 + bbase + g * 128];
        acc[g] = __builtin_amdgcn_mfma_f32_16x16x32_bf16(ah, bh, acc[g], 0, 0, 0);
        acc[g] = __builtin_amdgcn_mfma_f32_16x16x32_bf16(al, bh, acc[g], 0, 0, 0);
        acc[g] = __builtin_amdgcn_mfma_f32_16x16x32_bf16(ah, bl, acc[g], 0, 0, 0);
      }
    }

#pragma unroll
    for (int r = 0; r < 4; ++r) {
      const int m = m0 + w * 16 + lg * 4 + r;
      const float rg = sigm(bf2f(gr[r]) + acc[0][r] + bR);
      const float zg = sigm(bf2f(gz[r]) + acc[1][r] + bZ);
      const float ng = tanhf(bf2f(gn[r]) + rg * (acc[2][r] + bN));
      const float hn = (1.0f - zg) * ng + zg * hprev[r];
      hprev[r] = hn;
      const u16 hh = f2bf(hn);
      const u16 hl = f2bf(hn - bf2f(hh));
      coh_st32(&hd[(size_t)m * 512 + j], (u32)hh | ((u32)hl << 16));
      if ((mk[r] >> tok) & 1ull) ym[r] = fmaxf(ym[r], hn);
    }

    if (s < T_SEQ - 1) {
      __syncthreads();  // all waves' coherent h stores drained (vmcnt 0 at barrier)
      if (t == 0) {
        __hip_atomic_fetch_add(&bar[G * 32], 1, __ATOMIC_RELAXED, __HIP_MEMORY_SCOPE_AGENT);
        const int target = 32 * (s + 1);
        while (__hip_atomic_load(&bar[G * 32], __ATOMIC_RELAXED, __HIP_MEMORY_SCOPE_AGENT) <
               target)
          __builtin_amdgcn_s_sleep(2);
      }
      __syncthreads();
    }
  }

#pragma unroll
  for (int r = 0; r < 4; ++r) {
    const int m = m0 + w * 16 + lg * 4 + r;
    ymax[(size_t)m * 1024 + dir * 512 + j] = ym[r];
  }
}

extern "C" void kernel_launch(void* const* d_in, const int* in_sizes, int n_in,
                              void* d_out, int out_size, void* d_ws, size_t ws_size,
                              hipStream_t stream) {
  const int* idxs = (const int*)d_in[0];
  const float* emb = (const float*)d_in[1];
  const float* wihf = (const float*)d_in[2];
  const float* whhf = (const float*)d_in[3];
  const float* bihf = (const float*)d_in[4];
  const float* bhhf = (const float*)d_in[5];
  const float* wihb = (const float*)d_in[6];
  const float* whhb = (const float*)d_in[7];
  const float* bihb = (const float*)d_in[8];
  const float* bhhb = (const float*)d_in[9];
  float* ymax = (float*)d_out;  // [512][1024] f32

  char* ws = (char*)d_ws;
  u16* whh_hi = (u16*)(ws + 0);              //   3,145,728
  u16* whh_lo = (u16*)(ws + 3145728);        //   3,145,728
  u16* wih = (u16*)(ws + 6291456);           //   1,966,080
  float* bias_ih = (float*)(ws + 8257536);   //      12,288
  float* bias_hh = (float*)(ws + 8269824);   //      12,288
  u32* hpk = (u32*)(ws + 8282112);           //   4,194,304  [parity][dir][512][512] u32
  u64* mask = (u64*)(ws + 12476416);         //       4,096
  int* bar = (int*)(ws + 12480512);          //       1,024
  u16* gi = (u16*)(ws + 12481536);           // 125,829,120  bf16 [20480][3072]
  u16* emb16 = (u16*)(ws + 138310656);       //  32,000,000  bf16 [50000][320]
  const int use_emb16 = (ws_size >= 170310656ull) ? 1 : 0;

  k_init<<<2048, 256, 0, stream>>>(idxs, hpk, mask, bar);
  if (use_emb16) k_prep_emb<<<4096, 256, 0, stream>>>(emb, emb16);
  k_prep_wih<<<3072, 320, 0, stream>>>(wihf, wihb, wih);
  k_prep_whh<<<3072, 512, 0, stream>>>(whhf, whhb, whh_hi, whh_lo);
  k_prep_bias<<<3, 1024, 0, stream>>>(bihf, bihb, bhhf, bhhb, bias_ih, bias_hh);
  k_gi_gemm<<<dim3(160, 24), 256, 0, stream>>>(idxs, emb, emb16, use_emb16, wih, bias_ih, gi);

  hipFuncSetAttribute((const void*)k_gru_persist,
                      hipFuncAttributeMaxDynamicSharedMemorySize, 98304);
  k_gru_persist<<<dim3(256), dim3(512), 98304, stream>>>(whh_hi, whh_lo, bias_hh, gi, mask,
                                                         hpk, ymax, bar);
}